// Round 9
// baseline (1207.034 us; speedup 1.0000x reference)
//
#include <hip/hip_runtime.h>

// ---------------------------------------------------------------------------
// Grid attention v10, bf16 MFMA (gfx950). 4096 windows; n=49; D=512; 16h x 32.
// = v6 (793us: x,y LDS-staged once, 4 wave-pairs, N-split proj / M-split attn)
//   with projections fused 2-heads-per-pass: one set of x/y A-frag reads feeds
//   2 heads' B-streams (proj A-reads halved). Head B's q/k/v carried packed
//   in 24 VGPRs through head A's attention, unpacked to reused LDS scratch.
// LDS: xb 50176 | yb 50176 | 4 pairs x 14720 (qb 3136 | kb 3136 | vtA 4096 |
//   vtB 4096 | sb 256; P aliases qb+kb) = 159232 B.
// ws (2.5MB): Wq/Wk/Wv pre-swizzled B-frags + biasD (same as v2/v6).
// ---------------------------------------------------------------------------

typedef __bf16 bf16x8 __attribute__((ext_vector_type(8)));
typedef __attribute__((ext_vector_type(4))) float f32x4;

#define DEVI __device__ __forceinline__

DEVI unsigned short f2bf(float f) {  // round-to-nearest-even
  union { float f; unsigned u; } v; v.f = f;
  unsigned r = v.u + 0x7FFFu + ((v.u >> 16) & 1u);
  return (unsigned short)(r >> 16);
}
DEVI unsigned pkbf(float a, float b) {
  return (unsigned)f2bf(a) | ((unsigned)f2bf(b) << 16);
}
DEVI uint2 pk4(const f32x4& a) {
  uint2 r; r.x = pkbf(a[0], a[1]); r.y = pkbf(a[2], a[3]); return r;
}

#define MFMA16(a, b, c) __builtin_amdgcn_mfma_f32_16x16x32_bf16((a), (b), (c), 0, 0, 0)

// ---------------- prep: weights -> swizzled bf16 frags, bias -> D-layout ----
__global__ void prep_kernel(const float* __restrict__ Wq, const float* __restrict__ Wkv,
                            const float* __restrict__ bt, char* __restrict__ ws) {
  int t = blockIdx.x * 256 + threadIdx.x;
  if (t < 786432) {  // 3 * 16 * 2 * 16 * 64 * 8 bf16 elements
    int e = t & 7, lane = (t >> 3) & 63, ks = (t >> 9) & 15, nt = (t >> 13) & 1,
        h = (t >> 14) & 15, T = t >> 18;
    int row = ks * 32 + (lane >> 4) * 8 + e;     // K index in [0,512)
    int col = h * 32 + nt * 16 + (lane & 15);    // N index
    float v;
    if (T == 0)      v = Wq[row * 512 + col] * 0.17677669529663687f;  // fold 1/sqrt(32)
    else if (T == 1) v = Wkv[row * 1024 + col];
    else             v = Wkv[row * 1024 + 512 + col];
    ((unsigned short*)ws)[t] = f2bf(v);
  }
  if (t < 262144) {  // 16 * 4 * 4 * 64 * 4 f32
    int r = t & 3, lane = (t >> 2) & 63, nt = (t >> 8) & 3, mt = (t >> 10) & 3,
        h = (t >> 12) & 15;
    int i = mt * 16 + (lane >> 4) * 4 + r;
    int j = nt * 16 + (lane & 15);
    float v;
    if (j >= 49)      v = -1e30f;   // mask padded key columns
    else if (i >= 49) v = 0.0f;     // padded query rows: keep finite
    else {
      int hi = i / 7, wi = i % 7, hj = j / 7, wj = j % 7;
      v = bt[((hi - hj + 6) * 13 + (wi - wj + 6)) * 16 + h];
    }
    ((float*)(ws + 1572864))[t] = v;
  }
}

// ---------------- LDS fragment loaders (XOR-swizzled) -----------------------
// xb/yb: [49][512] bf16, row stride 1024B, swz bits 4-6
DEVI bf16x8 ldXY(const char* base, int row, int kc) {
  unsigned a = ((unsigned)(row * 1024 + kc * 2)) ^ (((unsigned)row & 7u) << 4);
  return *(const bf16x8*)(base + a);
}
DEVI bf16x8 ldXY_c(const char* base, int row, int kc) {
  int rc = row < 48 ? row : 48;
  bf16x8 v = ldXY(base, rc, kc);
  if (row > 48) {
    union { long long z[2]; bf16x8 v; } u; u.z[0] = 0; u.z[1] = 0;
    v = u.v;
  }
  return v;
}
// qb/kb: [49][32] bf16, row stride 64B, swz bits 4-5
DEVI bf16x8 ldQK(const char* base, int row, int kc) {
  int rc = row < 48 ? row : 48;
  unsigned a = ((unsigned)(rc * 64 + kc * 2)) ^ (((unsigned)rc & 3u) << 4);
  return *(const bf16x8*)(base + a);
}
// pb: [49][64] bf16, row stride 128B, swz bits 4-6
DEVI bf16x8 ldP(const char* base, int row, int kc) {
  int rc = row < 48 ? row : 48;
  unsigned a = ((unsigned)(rc * 128 + kc * 2)) ^ (((unsigned)rc & 7u) << 4);
  return *(const bf16x8*)(base + a);
}
// vt: [32][64] bf16 (V transposed: [dh][tok]), row stride 128B, swz bits 4-6
DEVI bf16x8 ldVT(const char* base, int dh, int kc) {
  unsigned a = ((unsigned)(dh * 128 + kc * 2)) ^ (((unsigned)dh & 7u) << 4);
  return *(const bf16x8*)(base + a);
}

// ---------------- main fused kernel ----------------------------------------
__global__ __launch_bounds__(512, 2)
void attn_kernel(const float* __restrict__ x, const float* __restrict__ y,
                 const char* __restrict__ wsW, const float* __restrict__ biasD,
                 float* __restrict__ out) {
  extern __shared__ char smem[];
  char* xb = smem;            // 50176
  char* yb = smem + 50176;    // 50176
  const int tid = threadIdx.x;
  const int lane = tid & 63, wave = tid >> 6;
  const int p = wave >> 1, sub = wave & 1;
  const int g = lane >> 4, lr = lane & 15;
  char* pbase = smem + 100352 + p * 14720;  // per-PAIR scratch
  char* qb = pbase;             // 3136 (current head q)
  char* kb = pbase + 3136;      // 3136 (current head k)
  char* vtA = pbase + 6272;     // 4096
  char* vtB = pbase + 10368;    // 4096
  char* pb = pbase;             // P aliases qb+kb (6272B) -- barrier-guarded
  float* sb = (float*)(pbase + 14464);  // 64 inv-sums

  const int bw = blockIdx.x;
  const float* xs = x + (size_t)bw * 25088;
  const float* ys = y + (size_t)bw * 25088;

  // ---- stage x,y windows to LDS as bf16 ----
  for (int it = tid; it < 6272; it += 512) {
    float4 v = ((const float4*)xs)[it];
    float4 w = ((const float4*)ys)[it];
    int i = it >> 7;               // row 0..48
    int k = (it & 127) << 2;       // col 0..508
    unsigned a = ((unsigned)(i * 1024 + k * 2)) ^ (((unsigned)i & 7u) << 4);
    uint2 ux, uy;
    ux.x = pkbf(v.x, v.y); ux.y = pkbf(v.z, v.w);
    uy.x = pkbf(w.x, w.y); uy.y = pkbf(w.z, w.w);
    *(uint2*)(xb + a) = ux;
    *(uint2*)(yb + a) = uy;
  }

  const bf16x8* wsQ = (const bf16x8*)wsW;
  const bf16x8* wsK = (const bf16x8*)(wsW + 524288);
  const bf16x8* wsV = (const bf16x8*)(wsW + 1048576);
  const f32x4* bD = (const f32x4*)biasD;
  const f32x4 fz = {0.f, 0.f, 0.f, 0.f};

  // store q/k acc (D-layout) -> [row][dh] u16 scatter (v6 pattern)
  auto storeQK = [&](char* dst, f32x4 (&acc)[4]) {
    #pragma unroll
    for (int mt = 0; mt < 4; ++mt)
      #pragma unroll
      for (int r = 0; r < 4; ++r) {
        int row = mt * 16 + g * 4 + r;
        if (row < 49) {
          unsigned a = ((unsigned)(row * 64 + (sub * 16 + lr) * 2)) ^ (((unsigned)row & 3u) << 4);
          *(unsigned short*)(dst + a) = f2bf(acc[mt][r]);
        }
      }
  };
  // store packed q/k (uint2 per tile) -> same scatter layout
  auto storeQKp = [&](char* dst, uint2 (&pk)[4]) {
    #pragma unroll
    for (int mt = 0; mt < 4; ++mt) {
      int row0 = mt * 16 + g * 4;
      unsigned colb = (unsigned)((sub * 16 + lr) * 2);
      unsigned u[4] = { pk[mt].x & 0xFFFFu, pk[mt].x >> 16,
                        pk[mt].y & 0xFFFFu, pk[mt].y >> 16 };
      #pragma unroll
      for (int r = 0; r < 4; ++r) {
        int row = row0 + r;
        if (row < 49) {
          unsigned a = ((unsigned)(row * 64) + colb) ^ (((unsigned)row & 3u) << 4);
          *(unsigned short*)(dst + a) = (unsigned short)u[r];
        }
      }
    }
  };
  // store v acc -> vt [dh][tok] packed uint2
  auto storeVT = [&](char* vt, f32x4 (&acc)[4]) {
    #pragma unroll
    for (int mt = 0; mt < 4; ++mt) {
      int dh = sub * 16 + lr;
      int t0 = mt * 16 + g * 4;
      unsigned a = ((unsigned)(dh * 128 + t0 * 2)) ^ (((unsigned)dh & 7u) << 4);
      *(uint2*)(vt + a) = pk4(acc[mt]);
    }
  };
  auto storeVTp = [&](char* vt, uint2 (&pk)[4]) {
    #pragma unroll
    for (int mt = 0; mt < 4; ++mt) {
      int dh = sub * 16 + lr;
      int t0 = mt * 16 + g * 4;
      unsigned a = ((unsigned)(dh * 128 + t0 * 2)) ^ (((unsigned)dh & 7u) << 4);
      *(uint2*)(vt + a) = pk[mt];
    }
  };

  // ---- attention for head h (v6 verbatim; vt selectable) ----
  auto attn_head = [&](int h, const char* vt) {
    f32x4 bias[2][4];
    #pragma unroll
    for (int mi = 0; mi < 2; ++mi)
      #pragma unroll
      for (int nt = 0; nt < 4; ++nt)
        bias[mi][nt] = bD[(size_t)(((h * 4 + sub * 2 + mi) * 4 + nt) * 64 + lane)];

    bf16x8 qa[2], kf[4];
    #pragma unroll
    for (int mi = 0; mi < 2; ++mi) qa[mi] = ldQK(qb, sub * 32 + mi * 16 + lr, g * 8);
    #pragma unroll
    for (int nt = 0; nt < 4; ++nt) kf[nt] = ldQK(kb, nt * 16 + lr, g * 8);
    f32x4 accs[2][4];
    #pragma unroll
    for (int mi = 0; mi < 2; ++mi)
      #pragma unroll
      for (int nt = 0; nt < 4; ++nt)
        accs[mi][nt] = MFMA16(qa[mi], kf[nt], fz);

    float sinv[2][4];
    #pragma unroll
    for (int mi = 0; mi < 2; ++mi) {
      f32x4 vals[4];
      #pragma unroll
      for (int nt = 0; nt < 4; ++nt) vals[nt] = accs[mi][nt] + bias[mi][nt];
      #pragma unroll
      for (int r = 0; r < 4; ++r) {
        float m = fmaxf(fmaxf(vals[0][r], vals[1][r]), fmaxf(vals[2][r], vals[3][r]));
        m = fmaxf(m, __shfl_xor(m, 1));
        m = fmaxf(m, __shfl_xor(m, 2));
        m = fmaxf(m, __shfl_xor(m, 4));
        m = fmaxf(m, __shfl_xor(m, 8));
        float s = 0.f;
        #pragma unroll
        for (int nt = 0; nt < 4; ++nt) {
          float pv = __expf(vals[nt][r] - m);
          vals[nt][r] = pv;
          s += pv;
        }
        s += __shfl_xor(s, 1);
        s += __shfl_xor(s, 2);
        s += __shfl_xor(s, 4);
        s += __shfl_xor(s, 8);
        sinv[mi][r] = 1.0f / s;
      }
      accs[mi][0] = vals[0]; accs[mi][1] = vals[1];
      accs[mi][2] = vals[2]; accs[mi][3] = vals[3];
    }

    __syncthreads();  // both waves done reading qb/kb frags -> pb may overwrite

    #pragma unroll
    for (int mi = 0; mi < 2; ++mi) {
      int mt_g = sub * 2 + mi;
      #pragma unroll
      for (int r = 0; r < 4; ++r) {
        int row = mt_g * 16 + g * 4 + r;
        if (row < 49) {
          #pragma unroll
          for (int nt = 0; nt < 4; ++nt) {
            unsigned a = ((unsigned)(row * 128 + (nt * 16 + lr) * 2)) ^ (((unsigned)row & 7u) << 4);
            *(unsigned short*)(pb + a) = f2bf(accs[mi][nt][r]);
          }
          if (lr == 0) sb[row] = sinv[mi][r];
        }
      }
    }

    f32x4 acco[2][2];
    acco[0][0] = fz; acco[0][1] = fz; acco[1][0] = fz; acco[1][1] = fz;
    #pragma unroll
    for (int ks = 0; ks < 2; ++ks) {
      int jc = ks * 32 + g * 8;
      bf16x8 av0 = ldVT(vt, lr, jc);
      bf16x8 av1 = ldVT(vt, lr + 16, jc);
      bf16x8 bp0 = ldP(pb, (sub * 2 + 0) * 16 + lr, jc);
      bf16x8 bp1 = ldP(pb, (sub * 2 + 1) * 16 + lr, jc);
      acco[0][0] = MFMA16(av0, bp0, acco[0][0]);
      acco[0][1] = MFMA16(av0, bp1, acco[0][1]);
      acco[1][0] = MFMA16(av1, bp0, acco[1][0]);
      acco[1][1] = MFMA16(av1, bp1, acco[1][1]);
    }

    float* ow = out + (size_t)bw * 25088 + h * 32;
    #pragma unroll
    for (int ntl = 0; ntl < 2; ++ntl) {
      int tok = (sub * 2 + ntl) * 16 + lr;
      if (tok < 49) {
        float inv = sb[tok];
        #pragma unroll
        for (int mt = 0; mt < 2; ++mt) {
          f32x4 vv = acco[mt][ntl];
          vv[0] *= inv; vv[1] *= inv; vv[2] *= inv; vv[3] *= inv;
          *(f32x4*)(&ow[(size_t)tok * 512 + mt * 16 + g * 4]) = vv;
        }
      }
    }
  };

  for (int hp = 0; hp < 2; ++hp) {
    const int hA = p * 4 + hp * 2, hB = hA + 1;

    __syncthreads();  // pair scratch free (prev group's attn reads done)

    // ---- fused Q-pass (heads A+B share A-frags), rolling 8-deep x 2 ----
    f32x4 aqA[4], aqB[4];
    #pragma unroll
    for (int mt = 0; mt < 4; ++mt) { aqA[mt] = fz; aqB[mt] = fz; }
    {
      const bf16x8* pQA = wsQ + (size_t)((hA * 2 + sub) * 16) * 64 + lane;
      const bf16x8* pQB = wsQ + (size_t)((hB * 2 + sub) * 16) * 64 + lane;
      bf16x8 ra[8], rb[8];
      #pragma unroll
      for (int i = 0; i < 8; ++i) { ra[i] = pQA[i * 64]; rb[i] = pQB[i * 64]; }
      #pragma unroll
      for (int ks = 0; ks < 16; ++ks) {
        bf16x8 fa = ra[ks & 7], fb = rb[ks & 7];
        if (ks < 8) { ra[ks & 7] = pQA[(ks + 8) * 64]; rb[ks & 7] = pQB[(ks + 8) * 64]; }
        int kc = ks * 32 + g * 8;
        bf16x8 a0 = ldXY(xb, lr, kc);
        bf16x8 a1 = ldXY(xb, lr + 16, kc);
        bf16x8 a2 = ldXY(xb, lr + 32, kc);
        bf16x8 a3 = ldXY_c(xb, lr + 48, kc);
        aqA[0] = MFMA16(a0, fa, aqA[0]);
        aqA[1] = MFMA16(a1, fa, aqA[1]);
        aqA[2] = MFMA16(a2, fa, aqA[2]);
        aqA[3] = MFMA16(a3, fa, aqA[3]);
        aqB[0] = MFMA16(a0, fb, aqB[0]);
        aqB[1] = MFMA16(a1, fb, aqB[1]);
        aqB[2] = MFMA16(a2, fb, aqB[2]);
        aqB[3] = MFMA16(a3, fb, aqB[3]);
      }
    }
    storeQK(qb, aqA);
    uint2 qBp[4];
    #pragma unroll
    for (int mt = 0; mt < 4; ++mt) qBp[mt] = pk4(aqB[mt]);

    // ---- fused KV-pass (heads A+B, 4 B-streams share A-frags), 4-deep ----
    f32x4 akA[4], avA[4], akB[4], avB[4];
    #pragma unroll
    for (int mt = 0; mt < 4; ++mt) {
      akA[mt] = fz; avA[mt] = fz; akB[mt] = fz; avB[mt] = fz;
    }
    {
      const bf16x8* pKA = wsK + (size_t)((hA * 2 + sub) * 16) * 64 + lane;
      const bf16x8* pKB = wsK + (size_t)((hB * 2 + sub) * 16) * 64 + lane;
      const bf16x8* pVA = wsV + (size_t)((hA * 2 + sub) * 16) * 64 + lane;
      const bf16x8* pVB = wsV + (size_t)((hB * 2 + sub) * 16) * 64 + lane;
      bf16x8 rkA[4], rkB[4], rvA[4], rvB[4];
      #pragma unroll
      for (int i = 0; i < 4; ++i) {
        rkA[i] = pKA[i * 64]; rkB[i] = pKB[i * 64];
        rvA[i] = pVA[i * 64]; rvB[i] = pVB[i * 64];
      }
      #pragma unroll
      for (int ks = 0; ks < 16; ++ks) {
        bf16x8 bkA = rkA[ks & 3], bkB = rkB[ks & 3];
        bf16x8 bvA = rvA[ks & 3], bvB = rvB[ks & 3];
        if (ks < 12) {
          rkA[ks & 3] = pKA[(ks + 4) * 64]; rkB[ks & 3] = pKB[(ks + 4) * 64];
          rvA[ks & 3] = pVA[(ks + 4) * 64]; rvB[ks & 3] = pVB[(ks + 4) * 64];
        }
        int kc = ks * 32 + g * 8;
        bf16x8 a0 = ldXY(yb, lr, kc);
        bf16x8 a1 = ldXY(yb, lr + 16, kc);
        bf16x8 a2 = ldXY(yb, lr + 32, kc);
        bf16x8 a3 = ldXY_c(yb, lr + 48, kc);
        akA[0] = MFMA16(a0, bkA, akA[0]);
        akA[1] = MFMA16(a1, bkA, akA[1]);
        akA[2] = MFMA16(a2, bkA, akA[2]);
        akA[3] = MFMA16(a3, bkA, akA[3]);
        avA[0] = MFMA16(a0, bvA, avA[0]);
        avA[1] = MFMA16(a1, bvA, avA[1]);
        avA[2] = MFMA16(a2, bvA, avA[2]);
        avA[3] = MFMA16(a3, bvA, avA[3]);
        akB[0] = MFMA16(a0, bkB, akB[0]);
        akB[1] = MFMA16(a1, bkB, akB[1]);
        akB[2] = MFMA16(a2, bkB, akB[2]);
        akB[3] = MFMA16(a3, bkB, akB[3]);
        avB[0] = MFMA16(a0, bvB, avB[0]);
        avB[1] = MFMA16(a1, bvB, avB[1]);
        avB[2] = MFMA16(a2, bvB, avB[2]);
        avB[3] = MFMA16(a3, bvB, avB[3]);
      }
    }
    storeQK(kb, akA);
    storeVT(vtA, avA);
    uint2 kBp[4], vBp[4];
    #pragma unroll
    for (int mt = 0; mt < 4; ++mt) { kBp[mt] = pk4(akB[mt]); vBp[mt] = pk4(avB[mt]); }

    __syncthreads();  // qA, kA, vtA visible

    attn_head(hA, vtA);   // internal barrier before P write

    __syncthreads();  // PV(A) done by both waves -> qb/kb (P) free

    // ---- unpack head B's q/k/v from registers into scratch ----
    storeQKp(qb, qBp);
    storeQKp(kb, kBp);
    storeVTp(vtB, vBp);

    __syncthreads();  // qB, kB, vtB visible

    attn_head(hB, vtB);   // internal barrier before P write
  }
}

extern "C" void kernel_launch(void* const* d_in, const int* in_sizes, int n_in,
                              void* d_out, int out_size, void* d_ws, size_t ws_size,
                              hipStream_t stream) {
  (void)in_sizes; (void)n_in; (void)out_size; (void)ws_size;
  const float* x = (const float*)d_in[0];
  const float* y = (const float*)d_in[1];
  const float* Wq = (const float*)d_in[2];
  const float* Wkv = (const float*)d_in[3];
  const float* bt = (const float*)d_in[4];
  float* out = (float*)d_out;
  char* ws = (char*)d_ws;

  prep_kernel<<<3072, 256, 0, stream>>>(Wq, Wkv, bt, ws);

  (void)hipFuncSetAttribute((const void*)attn_kernel,
                            hipFuncAttributeMaxDynamicSharedMemorySize, 159232);
  attn_kernel<<<4096, 512, 159232, stream>>>(x, y, (const char*)ws,
                                             (const float*)(ws + 1572864), out);
}

// Round 11
// 709.539 us; speedup vs baseline: 1.7012x; 1.7012x over previous
//
#include <hip/hip_runtime.h>

// ---------------------------------------------------------------------------
// Grid attention v12, bf16 MFMA (gfx950). 4096 windows; n=49; D=512; 16h x 32.
// = v6 memory discipline (x,y LDS-staged once, N-split proj, deep weight
//   preloads, full-stride vt all-tokens-written, P aliases qb+kb barrier-guarded)
// + v11/v8 attention math (swapped QK^T -> in-lane softmax, 8 shfl vs 64;
//   P normalized in-register, packed uint2 stores; conflict-free q/k swizzle).
// LDS = 141824: xb 50176 | yb 50176 | 4 pairs x 10368 (qb 3136|kb 3136|vt 4096)
// ws (2.5MB): Wq/Wk/Wv pre-swizzled B-frags + biasT (sim^T layout).
// ---------------------------------------------------------------------------

typedef __bf16 bf16x8 __attribute__((ext_vector_type(8)));
typedef __attribute__((ext_vector_type(4))) float f32x4;

#define DEVI __device__ __forceinline__

DEVI unsigned short f2bf(float f) {  // round-to-nearest-even
  union { float f; unsigned u; } v; v.f = f;
  unsigned r = v.u + 0x7FFFu + ((v.u >> 16) & 1u);
  return (unsigned short)(r >> 16);
}
DEVI unsigned pkbf(float a, float b) {
  return (unsigned)f2bf(a) | ((unsigned)f2bf(b) << 16);
}

#define MFMA16(a, b, c) __builtin_amdgcn_mfma_f32_16x16x32_bf16((a), (b), (c), 0, 0, 0)

#define SWZ_Y(r)  ((((unsigned)(r)) & 7u) << 4)
#define SWZ_A(r)  (((((unsigned)(r)) >> 2) & 3u) << 5)
#define SWZ_P(r)  ((((unsigned)(r)) & 7u) << 4)
#define SWZ_VT(r) ((((unsigned)(r)) & 7u) << 4)

// ---------------- prep: weights -> swizzled bf16 frags, bias -> sim^T layout
__global__ void prep_kernel(const float* __restrict__ Wq, const float* __restrict__ Wkv,
                            const float* __restrict__ bt, char* __restrict__ ws) {
  int t = blockIdx.x * 256 + threadIdx.x;
  if (t < 786432) {  // 3 * 16 * 2 * 16 * 64 * 8 bf16 elements
    int e = t & 7, lane = (t >> 3) & 63, ks = (t >> 9) & 15, nt = (t >> 13) & 1,
        h = (t >> 14) & 15, T = t >> 18;
    int row = ks * 32 + (lane >> 4) * 8 + e;     // K index in [0,512)
    int col = h * 32 + nt * 16 + (lane & 15);    // N index
    float v;
    if (T == 0)      v = Wq[row * 512 + col] * 0.17677669529663687f;  // fold 1/sqrt(32)
    else if (T == 1) v = Wkv[row * 1024 + col];
    else             v = Wkv[row * 1024 + 512 + col];
    ((unsigned short*)ws)[t] = f2bf(v);
  }
  if (t < 262144) {  // 16h * 4 i-tile * 4 j-tile * 64 lane * 4 reg, sim^T layout
    int r = t & 3, lane = (t >> 2) & 63, jt = (t >> 8) & 3, it = (t >> 10) & 3,
        h = (t >> 12) & 15;
    int i = it * 16 + (lane & 15);               // query: lane&15 = col of sim^T
    int j = jt * 16 + ((lane >> 4) & 3) * 4 + r; // key: regs = rows of sim^T
    float v;
    if (j >= 49)      v = -1e30f;   // mask padded key slots
    else if (i >= 49) v = 0.0f;     // padded query cols: keep finite
    else {
      int hi = i / 7, wi = i % 7, hj = j / 7, wj = j % 7;
      v = bt[((hi - hj + 6) * 13 + (wi - wj + 6)) * 16 + h];
    }
    ((float*)(ws + 1572864))[t] = v;
  }
}

// ---------------- LDS fragment loaders --------------------------------------
// xb/yb: [49][512] bf16, row stride 1024B, swz bits 4-6
DEVI bf16x8 ldXY(const char* base, int row, int kc) {
  unsigned a = ((unsigned)(row * 1024 + kc * 2)) ^ SWZ_Y(row);
  return *(const bf16x8*)(base + a);
}
DEVI bf16x8 ldXY_c(const char* base, int row, int kc) {
  int rc = row < 48 ? row : 48;
  bf16x8 v = ldXY(base, rc, kc);
  if (row > 48) {
    union { long long z[2]; bf16x8 v; } u; u.z[0] = 0; u.z[1] = 0;
    v = u.v;
  }
  return v;
}
// qb/kb: [49][32] bf16, row stride 64B, swz SWZ_A (conflict-free stores)
DEVI bf16x8 ldQK(const char* base, int row, int kc) {
  int rc = row < 48 ? row : 48;
  unsigned a = ((unsigned)(rc * 64 + kc * 2)) ^ SWZ_A(rc);
  return *(const bf16x8*)(base + a);
}
// P: [49][64] bf16 normalized, row = query i, swz SWZ_P
DEVI bf16x8 ldP2(const char* base, int row, int jc) {
  int rc = row < 48 ? row : 48;
  unsigned a = ((unsigned)(rc * 128 + jc * 2)) ^ SWZ_P(rc);
  return *(const bf16x8*)(base + a);
}
// vt: [32 dh][64 tok] bf16, row stride 128B, swz SWZ_VT (all tokens written)
DEVI bf16x8 ldVT(const char* base, int dh, int jc) {
  unsigned a = ((unsigned)(dh * 128 + jc * 2)) ^ SWZ_VT(dh);
  return *(const bf16x8*)(base + a);
}

// ---------------- main fused kernel ----------------------------------------
__global__ __launch_bounds__(512, 2)
void attn_kernel(const float* __restrict__ x, const float* __restrict__ y,
                 const char* __restrict__ wsW, const float* __restrict__ biasD,
                 float* __restrict__ out) {
  extern __shared__ char smem[];
  char* xb = smem;            // 50176
  char* yb = smem + 50176;    // 50176
  const int tid = threadIdx.x;
  const int lane = tid & 63, wave = tid >> 6;
  const int p = wave >> 1, sub = wave & 1;
  const int g = lane >> 4, lr = lane & 15;
  char* pbase = smem + 100352 + p * 10368;  // per-PAIR scratch
  char* qb = pbase;             // 3136
  char* kb = pbase + 3136;      // 3136
  char* vt = pbase + 6272;      // 4096
  char* Pb = pbase;             // P aliases qb+kb (6272B) -- barrier-guarded

  const int bw = blockIdx.x;
  const float* xs = x + (size_t)bw * 25088;
  const float* ys = y + (size_t)bw * 25088;

  // ---- stage x,y windows to LDS as bf16 ----
  for (int it = tid; it < 6272; it += 512) {
    float4 v = ((const float4*)xs)[it];
    float4 w = ((const float4*)ys)[it];
    int i = it >> 7;               // row 0..48
    int k = (it & 127) << 2;       // col 0..508
    unsigned a = ((unsigned)(i * 1024 + k * 2)) ^ SWZ_Y(i);
    uint2 ux, uy;
    ux.x = pkbf(v.x, v.y); ux.y = pkbf(v.z, v.w);
    uy.x = pkbf(w.x, w.y); uy.y = pkbf(w.z, w.w);
    *(uint2*)(xb + a) = ux;
    *(uint2*)(yb + a) = uy;
  }

  const bf16x8* wsQ = (const bf16x8*)wsW;
  const bf16x8* wsK = (const bf16x8*)(wsW + 524288);
  const bf16x8* wsV = (const bf16x8*)(wsW + 1048576);
  const f32x4* bD = (const f32x4*)biasD;
  const f32x4 fz = {0.f, 0.f, 0.f, 0.f};

  for (int hi = 0; hi < 4; ++hi) {
    const int h = p * 4 + hi;

    __syncthreads();  // scratch free: partner's attn reads of prev head done

    // ---- Q = Xw @ Wq_h, N-split (cols sub*16..+16), 16-frag preload ----
    f32x4 accq[4];
    #pragma unroll
    for (int mt = 0; mt < 4; ++mt) accq[mt] = fz;
    {
      const bf16x8* pQ = wsQ + (size_t)((h * 2 + sub) * 16) * 64 + lane;
      bf16x8 bq[16];
      #pragma unroll
      for (int ks = 0; ks < 16; ++ks) bq[ks] = pQ[ks * 64];
      #pragma unroll
      for (int ks = 0; ks < 16; ++ks) {
        int kc = ks * 32 + g * 8;
        accq[0] = MFMA16(ldXY(xb, lr, kc),        bq[ks], accq[0]);
        accq[1] = MFMA16(ldXY(xb, lr + 16, kc),   bq[ks], accq[1]);
        accq[2] = MFMA16(ldXY(xb, lr + 32, kc),   bq[ks], accq[2]);
        accq[3] = MFMA16(ldXY_c(xb, lr + 48, kc), bq[ks], accq[3]);
      }
    }
    // store q: [row][dh] u16 scatter, conflict-free swz
    #pragma unroll
    for (int mt = 0; mt < 4; ++mt)
      #pragma unroll
      for (int r = 0; r < 4; ++r) {
        int row = mt * 16 + g * 4 + r;
        if (row < 49) {
          unsigned a = ((unsigned)(row * 64 + (sub * 16 + lr) * 2)) ^ SWZ_A(row);
          *(unsigned short*)(qb + a) = f2bf(accq[mt][r]);
        }
      }

    // ---- K,V = Yw @ Wk_h / Wv_h, N-split, rolling 8-deep dual preload ----
    f32x4 acck[4], accv[4];
    #pragma unroll
    for (int mt = 0; mt < 4; ++mt) { acck[mt] = fz; accv[mt] = fz; }
    {
      const bf16x8* pK = wsK + (size_t)((h * 2 + sub) * 16) * 64 + lane;
      const bf16x8* pV = wsV + (size_t)((h * 2 + sub) * 16) * 64 + lane;
      bf16x8 ksr[8], vsr[8];
      #pragma unroll
      for (int i = 0; i < 8; ++i) { ksr[i] = pK[i * 64]; vsr[i] = pV[i * 64]; }
      #pragma unroll
      for (int ks = 0; ks < 16; ++ks) {
        bf16x8 bk = ksr[ks & 7], bv = vsr[ks & 7];
        if (ks < 8) {
          ksr[ks & 7] = pK[(ks + 8) * 64];
          vsr[ks & 7] = pV[(ks + 8) * 64];
        }
        int kc = ks * 32 + g * 8;
        bf16x8 a0 = ldXY(yb, lr, kc);
        bf16x8 a1 = ldXY(yb, lr + 16, kc);
        bf16x8 a2 = ldXY(yb, lr + 32, kc);
        bf16x8 a3 = ldXY_c(yb, lr + 48, kc);
        acck[0] = MFMA16(a0, bk, acck[0]);
        acck[1] = MFMA16(a1, bk, acck[1]);
        acck[2] = MFMA16(a2, bk, acck[2]);
        acck[3] = MFMA16(a3, bk, acck[3]);
        accv[0] = MFMA16(a0, bv, accv[0]);
        accv[1] = MFMA16(a1, bv, accv[1]);
        accv[2] = MFMA16(a2, bv, accv[2]);
        accv[3] = MFMA16(a3, bv, accv[3]);
      }
    }
    // store k (scatter u16, conflict-free swz) and vt (ALL 64 toks, finite)
    #pragma unroll
    for (int mt = 0; mt < 4; ++mt) {
      #pragma unroll
      for (int r = 0; r < 4; ++r) {
        int row = mt * 16 + g * 4 + r;
        if (row < 49) {
          unsigned a = ((unsigned)(row * 64 + (sub * 16 + lr) * 2)) ^ SWZ_A(row);
          *(unsigned short*)(kb + a) = f2bf(acck[mt][r]);
        }
      }
      int dh = sub * 16 + lr;
      int t0 = mt * 16 + g * 4;
      unsigned a = ((unsigned)(dh * 128 + t0 * 2)) ^ SWZ_VT(dh);
      uint2 pk;
      pk.x = pkbf(accv[mt][0], accv[mt][1]);
      pk.y = pkbf(accv[mt][2], accv[mt][3]);
      *(uint2*)(vt + a) = pk;
    }

    __syncthreads();  // q,k,vt visible to both waves of the pair

    // ======== attention (swapped QK^T; one alias-guard barrier) ========
    f32x4 bias[2][4];
    #pragma unroll
    for (int mi = 0; mi < 2; ++mi)
      #pragma unroll
      for (int jt = 0; jt < 4; ++jt)
        bias[mi][jt] = bD[(size_t)(((h * 4 + sub * 2 + mi) * 4 + jt) * 64 + lane)];

    // sim^T = MFMA(A=k, B=q): col = query i (lane&15), regs = key j
    bf16x8 qa[2], kf[4];
    #pragma unroll
    for (int mi = 0; mi < 2; ++mi) qa[mi] = ldQK(qb, sub * 32 + mi * 16 + lr, g * 8);
    #pragma unroll
    for (int jt = 0; jt < 4; ++jt) kf[jt] = ldQK(kb, jt * 16 + lr, g * 8);
    f32x4 accs[2][4];
    #pragma unroll
    for (int mi = 0; mi < 2; ++mi)
      #pragma unroll
      for (int jt = 0; jt < 4; ++jt)
        accs[mi][jt] = MFMA16(kf[jt], qa[mi], fz);

    // in-lane softmax (16 j-values/lane) + 2 shfl across g-replicas; normalize
    uint2 pks[2][4];
    #pragma unroll
    for (int mi = 0; mi < 2; ++mi) {
      f32x4 vals[4];
      #pragma unroll
      for (int jt = 0; jt < 4; ++jt) vals[jt] = accs[mi][jt] + bias[mi][jt];
      float m = vals[0][0];
      #pragma unroll
      for (int jt = 0; jt < 4; ++jt)
        #pragma unroll
        for (int r = 0; r < 4; ++r) m = fmaxf(m, vals[jt][r]);
      m = fmaxf(m, __shfl_xor(m, 16));
      m = fmaxf(m, __shfl_xor(m, 32));
      float s = 0.f;
      #pragma unroll
      for (int jt = 0; jt < 4; ++jt)
        #pragma unroll
        for (int r = 0; r < 4; ++r) {
          float pv = __expf(vals[jt][r] - m);
          vals[jt][r] = pv;
          s += pv;
        }
      s += __shfl_xor(s, 16);
      s += __shfl_xor(s, 32);
      float inv = 1.0f / s;
      #pragma unroll
      for (int jt = 0; jt < 4; ++jt) {
        pks[mi][jt].x = pkbf(vals[jt][0] * inv, vals[jt][1] * inv);
        pks[mi][jt].y = pkbf(vals[jt][2] * inv, vals[jt][3] * inv);
      }
    }

    __syncthreads();  // both waves done reading q/k -> P may overwrite alias

    // P write: packed uint2, own rows, conflict-free
    #pragma unroll
    for (int mi = 0; mi < 2; ++mi) {
      int i = sub * 32 + mi * 16 + lr;
      if (i < 49) {
        #pragma unroll
        for (int jt = 0; jt < 4; ++jt) {
          unsigned a = ((unsigned)(i * 128 + (jt * 16 + g * 4) * 2)) ^ SWZ_P(i);
          *(uint2*)(Pb + a) = pks[mi][jt];
        }
      }
    }

    // PV: out^T[dh][i] = V^T @ P^T ; A = vt rows (pair-shared), B = own P rows
    f32x4 acco[2][2];
    acco[0][0] = fz; acco[0][1] = fz; acco[1][0] = fz; acco[1][1] = fz;
    #pragma unroll
    for (int ks = 0; ks < 2; ++ks) {
      int jc = ks * 32 + g * 8;
      bf16x8 av0 = ldVT(vt, lr, jc);
      bf16x8 av1 = ldVT(vt, lr + 16, jc);
      bf16x8 bp0 = ldP2(Pb, sub * 32 + lr, jc);
      bf16x8 bp1 = ldP2(Pb, sub * 32 + 16 + lr, jc);
      acco[0][0] = MFMA16(av0, bp0, acco[0][0]);
      acco[0][1] = MFMA16(av0, bp1, acco[0][1]);
      acco[1][0] = MFMA16(av1, bp0, acco[1][0]);
      acco[1][1] = MFMA16(av1, bp1, acco[1][1]);
    }

    // store (already normalized): tok = col (lane&15), dh rows f32x4
    float* ow = out + (size_t)bw * 25088 + h * 32;
    #pragma unroll
    for (int it = 0; it < 2; ++it) {
      int tok = sub * 32 + it * 16 + lr;
      if (tok < 49) {
        #pragma unroll
        for (int md = 0; md < 2; ++md)
          *(f32x4*)(&ow[(size_t)tok * 512 + md * 16 + g * 4]) = acco[md][it];
      }
    }
  }
}

extern "C" void kernel_launch(void* const* d_in, const int* in_sizes, int n_in,
                              void* d_out, int out_size, void* d_ws, size_t ws_size,
                              hipStream_t stream) {
  (void)in_sizes; (void)n_in; (void)out_size; (void)ws_size;
  const float* x = (const float*)d_in[0];
  const float* y = (const float*)d_in[1];
  const float* Wq = (const float*)d_in[2];
  const float* Wkv = (const float*)d_in[3];
  const float* bt = (const float*)d_in[4];
  float* out = (float*)d_out;
  char* ws = (char*)d_ws;

  prep_kernel<<<3072, 256, 0, stream>>>(Wq, Wkv, bt, ws);

  (void)hipFuncSetAttribute((const void*)attn_kernel,
                            hipFuncAttributeMaxDynamicSharedMemorySize, 141824);
  attn_kernel<<<4096, 512, 141824, stream>>>(x, y, (const char*)ws,
                                             (const float*)(ws + 1572864), out);
}